// Round 5
// baseline (207.626 us; speedup 1.0000x reference)
//
#include <hip/hip_runtime.h>
#include <cstdint>

static constexpr int C     = 5;
static constexpr int MAXP  = 10;
static constexpr int MAXV  = 160000;
static constexpr int BLK   = 256;
static constexpr int RB    = 2048;         // hash buckets
static constexpr int BCAP  = 1024;         // bucket capacity for LDS sort (lambda~581 + guard)
static constexpr int EPT   = 8;
static constexpr int ELEMS = BLK * EPT;    // 2048 elements per block

// Output layout (float32, concatenated in reference return order)
static constexpr int VOX_OFF = 0;                           // 160000*10*5
static constexpr int CO_OFF  = MAXV * MAXP * C;             // 8,000,000
static constexpr int NPV_OFF = CO_OFF + MAXV * 3;           // 8,480,000
static constexpr int VN_OFF  = NPV_OFF + MAXV;              // 8,640,000

typedef unsigned long long u64;
static constexpr u64 BYTEMUL = 0x0101010101010101ull;

// Injective partition: equal lins always share a bucket; inter-bucket order is
// irrelevant (vid comes from first-appearance rank via flags, not sort order).
__device__ __forceinline__ int hashb(int k) {
    return (int)(((uint32_t)k * 2654435761u) >> 21);        // 11 bits -> [0,2048)
}

// K1: quantize -> key0 (-1 = invalid), per-block bucket histogram,
// fused zero-fill of output + flags8 (grid-stride).
__global__ void vx_prep(const float* __restrict__ pts, const float* __restrict__ vsz,
                        const float* __restrict__ crg, int* __restrict__ key0,
                        int* __restrict__ hist, u64* __restrict__ flags8,
                        float* __restrict__ out, int NP, int NP8) {
    __shared__ int sh[RB];
    int t = threadIdx.x, b = blockIdx.x;
    for (int d = t; d < RB; d += BLK) sh[d] = 0;
    float vx = vsz[0], vy = vsz[1], vz = vsz[2];
    float x0 = crg[0], y0 = crg[1], z0 = crg[2];
    int gx = (int)rintf((crg[3] - x0) / vx);
    int gy = (int)rintf((crg[4] - y0) / vy);
    int gz = (int)rintf((crg[5] - z0) / vz);
    __syncthreads();
    int base = b * ELEMS;
    #pragma unroll
    for (int r = 0; r < EPT; r++) {
        int i = base + r * BLK + t;
        if (i < NP) {
            float px = pts[i * C], py = pts[i * C + 1], pz = pts[i * C + 2];
            int cx = (int)floorf((px - x0) / vx);
            int cy = (int)floorf((py - y0) / vy);
            int cz = (int)floorf((pz - z0) / vz);
            bool valid = (cx >= 0) & (cx < gx) & (cy >= 0) & (cy < gy) & (cz >= 0) & (cz < gz);
            int k = (cx * gy + cy) * gz + cz;
            key0[i] = valid ? k : -1;
            if (valid) atomicAdd(&sh[hashb(k)], 1);
        }
    }
    __syncthreads();
    for (int d = t; d < RB; d += BLK) hist[b * RB + d] = sh[d];
    // fused zero-fill (out is float4-aligned; VN_OFF divisible by 4)
    int tid = b * BLK + t, nth = gridDim.x * BLK;
    float4* out4 = (float4*)out;
    const float4 z4 = make_float4(0.f, 0.f, 0.f, 0.f);
    for (int i = tid; i < VN_OFF / 4; i += nth) out4[i] = z4;
    for (int i = tid; i < NP8; i += nth) flags8[i] = 0ull;
}

// K2: wave-per-bucket exclusive scan across blocks (grid = RB/4 = 512).
__global__ void vx_scanw(int* __restrict__ hist, int* __restrict__ dtot, int NB) {
    int t = threadIdx.x;
    int lane = t & 63;
    int d = blockIdx.x * 4 + (t >> 6);
    int carry = 0;
    for (int base = 0; base < NB; base += 64) {
        int b = base + lane;
        int v = (b < NB) ? hist[b * RB + d] : 0;
        int x = v;
        #pragma unroll
        for (int o = 1; o < 64; o <<= 1) {
            int y = __shfl_up(x, o, 64);
            if (lane >= o) x += y;
        }
        if (b < NB) hist[b * RB + d] = carry + x - v;        // exclusive
        carry += __shfl(x, 63, 64);
    }
    if (lane == 0) dtot[d] = carry;
}

// K3: UNSTABLE bucket scatter (LDS-atomic slot grab). Stability is restored by
// the per-bucket (k,idx)-u64 sort in vx_bsort — so no ballot/whist machinery.
// Invalid points (key0 < 0) are dropped here; buckets are tightly packed.
__global__ void vx_scat(const int* __restrict__ key0, const int* __restrict__ hist,
                        const int* __restrict__ dtot, u64* __restrict__ pairA, int NP) {
    __shared__ int cnt[RB];
    int t = threadIdx.x, b = blockIdx.x;
    int lane = t & 63;
    if (t < 64) {                           // cross-bucket bases: 32 buckets/lane
        int loc[32]; int run = 0;
        #pragma unroll
        for (int j = 0; j < 32; j++) { loc[j] = run; run += dtot[t * 32 + j]; }
        int tot = run;
        for (int o = 1; o < 64; o <<= 1) {
            int x = __shfl_up(tot, o, 64);
            if (lane >= o) tot += x;
        }
        int excl = tot - run;
        #pragma unroll
        for (int j = 0; j < 32; j++) cnt[t * 32 + j] = excl + loc[j];
    }
    __syncthreads();
    for (int d = t; d < RB; d += BLK) cnt[d] += hist[b * RB + d];
    __syncthreads();
    int base = b * ELEMS;
    #pragma unroll
    for (int r = 0; r < EPT; r++) {
        int i = base + r * BLK + t;
        if (i < NP) {
            int k = key0[i];
            if (k >= 0) {
                int pos = atomicAdd(&cnt[hashb(k)], 1);
                pairA[pos] = ((u64)(uint32_t)k << 32) | (uint32_t)i;
            }
        }
    }
}

// K4: per-bucket bitonic sort of u64 (k,idx) pairs — HYBRID register/LDS.
// Thread t owns elements t and t+512 (2 regs). Stages with stride j<=32 run as
// __shfl_xor (no barrier, no LDS); j=512 is in-thread; only j in {64,128,256}
// (9 of 55 stages) touch LDS, with wave-consecutive (conflict-free) addressing.
// r4's full-LDS version: 55 barriered stages, 5.27M bank-conflict cycles, 47us.
__global__ void __launch_bounds__(512) vx_bsort(u64* __restrict__ pairA,
                                                const int* __restrict__ dtot,
                                                u64* __restrict__ flags8) {
    __shared__ u64 sp[BCAP];
    __shared__ int sb[2];
    int t = threadIdx.x, d = blockIdx.x;
    if (t < 64) {                           // start = sum dtot[0..d)
        int acc = 0;
        for (int j = t; j < d; j += 64) acc += dtot[j];
        #pragma unroll
        for (int o = 32; o > 0; o >>= 1) acc += __shfl_down(acc, o, 64);
        if (t == 0) { sb[0] = acc; sb[1] = dtot[d]; }
    }
    __syncthreads();
    int start = sb[0], size = sb[1];
    if (size <= 0) return;                  // uniform per block
    if (size > BCAP) size = BCAP;           // statistically unreachable guard
    u64 v0 = (t < size) ? pairA[start + t] : ~0ull;
    u64 v1 = (t + 512 < size) ? pairA[start + 512 + t] : ~0ull;
    for (int k2 = 2; k2 <= BCAP; k2 <<= 1) {
        bool up0 = ((t & k2) == 0);                  // e0 = t (< 512)
        bool up1 = (((t + 512) & k2) == 0);          // e1 = t + 512
        for (int j = k2 >> 1; j >= 64; j >>= 1) {
            if (j == 512) {                          // in-thread pair (t, t+512)
                u64 mn = v0 < v1 ? v0 : v1, mx = v0 < v1 ? v1 : v0;
                v0 = up0 ? mn : mx;                  // e0 has j-bit clear
                v1 = up1 ? mx : mn;                  // e1 has j-bit set
            } else {                                 // j in {64,128,256}: LDS
                __syncthreads();                     // prev reads done
                sp[t] = v0; sp[t + 512] = v1;
                __syncthreads();
                u64 p0 = sp[t ^ j];
                u64 p1 = sp[(t ^ j) + 512];
                bool l = (t & j) == 0;
                u64 mn0 = v0 < p0 ? v0 : p0, mx0 = v0 < p0 ? p0 : v0;
                v0 = (l == up0) ? mn0 : mx0;
                u64 mn1 = v1 < p1 ? v1 : p1, mx1 = v1 < p1 ? p1 : v1;
                v1 = (l == up1) ? mn1 : mx1;
            }
        }
        int jt = (k2 >> 1) < 32 ? (k2 >> 1) : 32;
        for (int j = jt; j >= 1; j >>= 1) {          // wave-local: shfl_xor
            u64 p0 = __shfl_xor(v0, j, 64);
            u64 p1 = __shfl_xor(v1, j, 64);
            bool l = (t & j) == 0;
            u64 mn0 = v0 < p0 ? v0 : p0, mx0 = v0 < p0 ? p0 : v0;
            v0 = (l == up0) ? mn0 : mx0;
            u64 mn1 = v1 < p1 ? v1 : p1, mx1 = v1 < p1 ? p1 : v1;
            v1 = (l == up1) ? mn1 : mx1;
        }
    }
    __syncthreads();
    sp[t] = v0; sp[t + 512] = v1;
    __syncthreads();
    unsigned char* flags = (unsigned char*)flags8;
    for (int i = t; i < size; i += 512) {
        u64 p = sp[i];
        pairA[start + i] = p;
        bool head = (i == 0) || ((p >> 32) != (sp[i - 1] >> 32));
        if (head) flags[(uint32_t)(p & 0xFFFFFFFFull)] = 1;
    }
}

// K5: per-block bytesum of flag words (publishes partials for wp2's walk).
__global__ void vx_wpA(const u64* __restrict__ flags8, int* __restrict__ wsum, int NP8) {
    __shared__ int s[BLK];
    int t = threadIdx.x, i = blockIdx.x * BLK + t;
    u64 wv = (i < NP8) ? flags8[i] : 0ull;
    s[t] = (int)((wv * BYTEMUL) >> 56);
    __syncthreads();
    for (int o = BLK / 2; o > 0; o >>= 1) { if (t < o) s[t] += s[t + o]; __syncthreads(); }
    if (t == 0) wsum[blockIdx.x] = s[0];
}

// K6: no-spin walk over wsum + in-block scan -> wpfx; last block writes voxel_num
// (G = total head count = total flag bytes).
__global__ void vx_wp2(const u64* __restrict__ flags8, const int* __restrict__ wsum,
                       int* __restrict__ wpfx, float* __restrict__ out_vnum, int NP8) {
    __shared__ int s[BLK];
    __shared__ int eS;
    int t = threadIdx.x, b = blockIdx.x;
    if (t < 64) {
        int acc = 0;
        for (int base = 0; base < b; base += 64) {
            int idx = base + t;
            int v = (idx < b) ? wsum[idx] : 0;
            #pragma unroll
            for (int o = 32; o > 0; o >>= 1) v += __shfl_down(v, o, 64);
            acc += v;
        }
        if (t == 0) eS = acc;
    }
    int i = b * BLK + t;
    u64 wv = (i < NP8) ? flags8[i] : 0ull;
    int v = (int)((wv * BYTEMUL) >> 56);
    s[t] = v;
    __syncthreads();                        // also publishes eS
    for (int o = 1; o < BLK; o <<= 1) {
        int x = (t >= o) ? s[t - o] : 0; __syncthreads();
        s[t] += x; __syncthreads();
    }
    if (i < NP8) wpfx[i] = eS + s[t] - v;
    if (b == gridDim.x - 1 && t == BLK - 1) {
        int G = eS + s[t];
        out_vnum[0] = (float)(G < MAXV ? G : MAXV);
    }
}

__device__ __forceinline__ int vox_rank(const u64* flags8, const int* wpfx, int io) {
    int w = io >> 3, b8 = io & 7;
    u64 below = flags8[w] & ((1ull << (8 * b8)) - 1ull);
    return wpfx[w] + (int)((below * BYTEMUL) >> 56);
}

// K7: bucket-geometry emit. Group start/end are bucket-local (gpos), vid via
// flags-rank of the head's original index. No gstart/ghead/ctrl arrays needed.
__global__ void vx_emit(const u64* __restrict__ pairA, const int* __restrict__ dtot,
                        const u64* __restrict__ flags8, const int* __restrict__ wpfx,
                        const float* __restrict__ pts, const float* __restrict__ vsz,
                        const float* __restrict__ crg, float* __restrict__ out) {
    __shared__ u64 sp[BCAP];
    __shared__ int gpos[BCAP + 1];
    __shared__ int s[BLK];
    __shared__ int sb[2];
    int t = threadIdx.x, d = blockIdx.x;
    if (t < 64) {
        int acc = 0;
        for (int j = t; j < d; j += 64) acc += dtot[j];
        #pragma unroll
        for (int o = 32; o > 0; o >>= 1) acc += __shfl_down(acc, o, 64);
        if (t == 0) { sb[0] = acc; sb[1] = dtot[d]; }
    }
    __syncthreads();
    int start = sb[0], size = sb[1];
    if (size <= 0) return;
    if (size > BCAP) size = BCAP;
    for (int i = t; i < size; i += BLK) sp[i] = pairA[start + i];
    __syncthreads();
    const int EL = BCAP / BLK;              // 4 local elements per thread
    int i0 = t * EL;
    unsigned hbits = 0; int hcnt = 0;
    #pragma unroll
    for (int r = 0; r < EL; r++) {
        int i = i0 + r;
        if (i < size) {
            int k = (int)(sp[i] >> 32);
            int h = (i == 0) || (k != (int)(sp[i - 1] >> 32));
            hbits |= (unsigned)h << r;
            hcnt += h;
        }
    }
    s[t] = hcnt;
    __syncthreads();
    for (int o = 1; o < BLK; o <<= 1) {
        int x = (t >= o) ? s[t - o] : 0; __syncthreads();
        s[t] += x; __syncthreads();
    }
    int gbase = s[t] - hcnt;                // heads before this thread's chunk
    {
        int g = gbase;
        #pragma unroll
        for (int r = 0; r < EL; r++)
            if ((hbits >> r) & 1) gpos[g++] = i0 + r;
    }
    int NG = s[BLK - 1];                    // total groups in bucket (>=1)
    if (t == 0) gpos[NG] = size;
    __syncthreads();
    int gyd = (int)rintf((crg[4] - crg[1]) / vsz[1]);
    int gzd = (int)rintf((crg[5] - crg[2]) / vsz[2]);
    int gg = gbase - 1;                     // group of element before chunk
    int cgg = -2, cvid = 0, cp0 = 0, cp1 = 0;
    #pragma unroll
    for (int r = 0; r < EL; r++) {
        int i = i0 + r;
        if (i >= size) break;
        int h = (hbits >> r) & 1;
        gg += h;
        u64 p = sp[i];
        int k = (int)(p >> 32);
        if (gg != cgg) {
            cgg = gg;
            cp0 = gpos[gg];
            cp1 = gpos[gg + 1];
            cvid = vox_rank(flags8, wpfx, (int)(sp[cp0] & 0xFFFFFFFFull));
        }
        if (cvid >= MAXV) continue;
        if (h) {                            // per-voxel work (once per group)
            int cz = k % gzd; int rr = k / gzd; int cy = rr % gyd; int cx = rr / gyd;
            out[CO_OFF + cvid * 3 + 0] = (float)cz;
            out[CO_OFF + cvid * 3 + 1] = (float)cy;
            out[CO_OFF + cvid * 3 + 2] = (float)cx;
            int gsz = cp1 - cp0;
            out[NPV_OFF + cvid] = (float)(gsz < MAXP ? gsz : MAXP);
        }
        int slot = i - cp0;
        if (slot >= MAXP) continue;
        int io = (int)(p & 0xFFFFFFFFull);
        const float* src = pts + io * C;
        float* dst = out + (cvid * MAXP + slot) * C;
        dst[0] = src[0]; dst[1] = src[1]; dst[2] = src[2]; dst[3] = src[3]; dst[4] = src[4];
    }
}

extern "C" void kernel_launch(void* const* d_in, const int* in_sizes, int n_in,
                              void* d_out, int out_size, void* d_ws, size_t ws_size,
                              hipStream_t stream) {
    if (!d_out || !d_ws || n_in < 3) return;
    const float* pts = (const float*)d_in[0];
    const float* vsz = (const float*)d_in[1];
    const float* crg = (const float*)d_in[2];
    if (!pts || !vsz || !crg) return;
    const int NP  = in_sizes[0] / C;
    if (NP <= 0) return;
    const int NB  = (NP + ELEMS - 1) / ELEMS;     // 2048-elem blocks (586)
    const int NP8 = (NP + 7) / 8;                 // byte-flag u64 words (150000)
    const int NWB = (NP8 + BLK - 1) / BLK;        // wp blocks (586)

    size_t need = (size_t)NP * 8ull                         // pairA
                + (size_t)NP * 4ull                         // key0
                + (size_t)RB * NB * 4ull                    // hist
                + (size_t)RB * 4ull                         // dtot
                + (size_t)NP8 * 8ull                        // flags8
                + (size_t)NP8 * 4ull                        // wpfx
                + (size_t)NWB * 4ull + 64ull;               // wsum + pad
    if (ws_size < need) return;
    if ((size_t)out_size < (size_t)VN_OFF + 1) return;

    u64* pairA  = (u64*)d_ws;
    int* key0   = (int*)(pairA + NP);
    int* hist   = key0 + NP;
    int* dtot   = hist + (size_t)RB * NB;
    u64* flags8 = (u64*)(dtot + RB);              // 8B-aligned (offset even #ints)
    int* wpfx   = (int*)(flags8 + NP8);
    int* wsum   = wpfx + NP8;
    float* out  = (float*)d_out;

    vx_prep<<<NB, BLK, 0, stream>>>(pts, vsz, crg, key0, hist, flags8, out, NP, NP8);
    vx_scanw<<<RB / 4, BLK, 0, stream>>>(hist, dtot, NB);
    vx_scat<<<NB, BLK, 0, stream>>>(key0, hist, dtot, pairA, NP);
    vx_bsort<<<RB, 512, 0, stream>>>(pairA, dtot, flags8);
    vx_wpA<<<NWB, BLK, 0, stream>>>(flags8, wsum, NP8);
    vx_wp2<<<NWB, BLK, 0, stream>>>(flags8, wsum, wpfx, out + VN_OFF, NP8);
    vx_emit<<<RB, BLK, 0, stream>>>(pairA, dtot, flags8, wpfx, pts, vsz, crg, out);
}

// Round 6
// 180.198 us; speedup vs baseline: 1.1522x; 1.1522x over previous
//
#include <hip/hip_runtime.h>
#include <cstdint>

static constexpr int C     = 5;
static constexpr int MAXP  = 10;
static constexpr int MAXV  = 160000;
static constexpr int BLK   = 256;
static constexpr int RB    = 2048;         // hash buckets
static constexpr int BCAP  = 1024;         // bucket capacity (lambda~571 + guard)
static constexpr int EPT   = 8;
static constexpr int ELEMS = BLK * EPT;    // 2048 elements per block

// Output layout (float32, concatenated in reference return order)
static constexpr int VOX_OFF = 0;                           // 160000*10*5
static constexpr int CO_OFF  = MAXV * MAXP * C;             // 8,000,000
static constexpr int NPV_OFF = CO_OFF + MAXV * 3;           // 8,480,000
static constexpr int VN_OFF  = NPV_OFF + MAXV;              // 8,640,000

typedef unsigned long long u64;
static constexpr u64 BYTEMUL = 0x0101010101010101ull;

// Bucket partition: equal lins always share a bucket; inter-bucket order is
// irrelevant (vid comes from first-appearance rank via flags, not sort order).
__device__ __forceinline__ int hashb(int k) {
    return (int)(((uint32_t)k * 2654435761u) >> 21);        // 11 bits -> [0,2048)
}

// K1: quantize -> key0 (-1 = invalid), per-block bucket histogram,
// fused zero-fill of output + flags8 (grid-stride).
__global__ void vx_prep(const float* __restrict__ pts, const float* __restrict__ vsz,
                        const float* __restrict__ crg, int* __restrict__ key0,
                        int* __restrict__ hist, u64* __restrict__ flags8,
                        float* __restrict__ out, int NP, int NP8) {
    __shared__ int sh[RB];
    int t = threadIdx.x, b = blockIdx.x;
    for (int d = t; d < RB; d += BLK) sh[d] = 0;
    float vx = vsz[0], vy = vsz[1], vz = vsz[2];
    float x0 = crg[0], y0 = crg[1], z0 = crg[2];
    int gx = (int)rintf((crg[3] - x0) / vx);
    int gy = (int)rintf((crg[4] - y0) / vy);
    int gz = (int)rintf((crg[5] - z0) / vz);
    __syncthreads();
    int base = b * ELEMS;
    #pragma unroll
    for (int r = 0; r < EPT; r++) {
        int i = base + r * BLK + t;
        if (i < NP) {
            float px = pts[i * C], py = pts[i * C + 1], pz = pts[i * C + 2];
            int cx = (int)floorf((px - x0) / vx);
            int cy = (int)floorf((py - y0) / vy);
            int cz = (int)floorf((pz - z0) / vz);
            bool valid = (cx >= 0) & (cx < gx) & (cy >= 0) & (cy < gy) & (cz >= 0) & (cz < gz);
            int k = (cx * gy + cy) * gz + cz;
            key0[i] = valid ? k : -1;
            if (valid) atomicAdd(&sh[hashb(k)], 1);
        }
    }
    __syncthreads();
    for (int d = t; d < RB; d += BLK) hist[b * RB + d] = sh[d];
    // fused zero-fill (out is float4-aligned; VN_OFF divisible by 4)
    int tid = b * BLK + t, nth = gridDim.x * BLK;
    float4* out4 = (float4*)out;
    const float4 z4 = make_float4(0.f, 0.f, 0.f, 0.f);
    for (int i = tid; i < VN_OFF / 4; i += nth) out4[i] = z4;
    for (int i = tid; i < NP8; i += nth) flags8[i] = 0ull;
}

// K2: wave-per-bucket exclusive scan across blocks (grid = RB/4 = 512).
__global__ void vx_scanw(int* __restrict__ hist, int* __restrict__ dtot, int NB) {
    int t = threadIdx.x;
    int lane = t & 63;
    int d = blockIdx.x * 4 + (t >> 6);
    int carry = 0;
    for (int base = 0; base < NB; base += 64) {
        int b = base + lane;
        int v = (b < NB) ? hist[b * RB + d] : 0;
        int x = v;
        #pragma unroll
        for (int o = 1; o < 64; o <<= 1) {
            int y = __shfl_up(x, o, 64);
            if (lane >= o) x += y;
        }
        if (b < NB) hist[b * RB + d] = carry + x - v;        // exclusive
        carry += __shfl(x, 63, 64);
    }
    if (lane == 0) dtot[d] = carry;
}

// K3: UNSTABLE bucket scatter (LDS-atomic slot grab). Canonical within-bucket
// order is restored by vx_group's hash-group + exact idx-rank.
__global__ void vx_scat(const int* __restrict__ key0, const int* __restrict__ hist,
                        const int* __restrict__ dtot, u64* __restrict__ pairA, int NP) {
    __shared__ int cnt[RB];
    int t = threadIdx.x, b = blockIdx.x;
    int lane = t & 63;
    if (t < 64) {                           // cross-bucket bases: 32 buckets/lane
        int loc[32]; int run = 0;
        #pragma unroll
        for (int j = 0; j < 32; j++) { loc[j] = run; run += dtot[t * 32 + j]; }
        int tot = run;
        for (int o = 1; o < 64; o <<= 1) {
            int x = __shfl_up(tot, o, 64);
            if (lane >= o) tot += x;
        }
        int excl = tot - run;
        #pragma unroll
        for (int j = 0; j < 32; j++) cnt[t * 32 + j] = excl + loc[j];
    }
    __syncthreads();
    for (int d = t; d < RB; d += BLK) cnt[d] += hist[b * RB + d];
    __syncthreads();
    int base = b * ELEMS;
    #pragma unroll
    for (int r = 0; r < EPT; r++) {
        int i = base + r * BLK + t;
        if (i < NP) {
            int k = key0[i];
            if (k >= 0) {
                int pos = atomicAdd(&cnt[hashb(k)], 1);
                pairA[pos] = ((u64)(uint32_t)k << 32) | (uint32_t)i;
            }
        }
    }
}

// K4: hash-group + exact idx-rank (replaces bitonic sort; r5 showed O(n log^2 n)
// bitonic is DS/VALU-pipe-bound at ~800 ops/thread; groups avg ~1.2 elements so
// grouping + O(g) ranking is ~25 ops/thread).
// Output layout contract identical to a (k,idx) sort: groups contiguous,
// idx-ascending within group, adjacent segments differ in k. rank-0 = min idx
// = group head -> sets flags byte.
__global__ void __launch_bounds__(512) vx_group(u64* __restrict__ pairA,
                                                const int* __restrict__ dtot,
                                                u64* __restrict__ flags8) {
    __shared__ int htab[BCAP];          // insert: key per slot (-1 empty); then fill ctr
    __shared__ int cnt[BCAP];           // per-slot count
    __shared__ int seg[BCAP];           // exclusive prefix (segment starts)
    __shared__ u64 sq[BCAP];            // grouped members (unordered within group)
    __shared__ int swp[8];              // per-wave scan partials
    __shared__ int sb[2];
    int t = threadIdx.x, d = blockIdx.x;
    if (t < 64) {                       // start = sum dtot[0..d)
        int acc = 0;
        for (int j = t; j < d; j += 64) acc += dtot[j];
        #pragma unroll
        for (int o = 32; o > 0; o >>= 1) acc += __shfl_down(acc, o, 64);
        if (t == 0) { sb[0] = acc; sb[1] = dtot[d]; }
    }
    for (int i = t; i < BCAP; i += 512) { htab[i] = -1; cnt[i] = 0; }
    __syncthreads();
    int start = sb[0], size = sb[1];
    if (size <= 0) return;              // uniform per block
    if (size > BCAP) size = BCAP;       // statistically unreachable guard
    bool a0 = t < size, a1 = t + 512 < size;
    u64 e0 = a0 ? pairA[start + t] : 0;
    u64 e1 = a1 ? pairA[start + 512 + t] : 0;
    int k0 = (int)(e0 >> 32), k1 = (int)(e1 >> 32);
    // hash-insert (open addressing; bounded probes: never hang)
    int s0 = 0, s1 = 0;
    if (a0) {
        s0 = (int)(((uint32_t)k0 * 0x85EBCA77u) >> 22);
        for (int it = 0; it < BCAP; ++it) {
            int old = atomicCAS(&htab[s0], -1, k0);
            if (old == -1 || old == k0) break;
            s0 = (s0 + 1) & (BCAP - 1);
        }
        atomicAdd(&cnt[s0], 1);
    }
    if (a1) {
        s1 = (int)(((uint32_t)k1 * 0x85EBCA77u) >> 22);
        for (int it = 0; it < BCAP; ++it) {
            int old = atomicCAS(&htab[s1], -1, k1);
            if (old == -1 || old == k1) break;
            s1 = (s1 + 1) & (BCAP - 1);
        }
        atomicAdd(&cnt[s1], 1);
    }
    __syncthreads();
    // exclusive scan of cnt[0..1023] -> seg (2 vals/thread, wave-scan + partials)
    int c0 = cnt[2 * t], c1 = cnt[2 * t + 1];
    int v = c0 + c1;
    int lane = t & 63, wv = t >> 6;
    int x = v;
    #pragma unroll
    for (int o = 1; o < 64; o <<= 1) {
        int y = __shfl_up(x, o, 64);
        if (lane >= o) x += y;
    }
    if (lane == 63) swp[wv] = x;
    // recycle htab as per-slot fill counters (all probes done)
    for (int i = t; i < BCAP; i += 512) htab[i] = 0;
    __syncthreads();
    if (t == 0) {
        int acc = 0;
        #pragma unroll
        for (int j = 0; j < 8; j++) { int tmp = swp[j]; swp[j] = acc; acc += tmp; }
    }
    __syncthreads();
    int excl = swp[wv] + x - v;
    seg[2 * t] = excl;
    seg[2 * t + 1] = excl + c0;
    __syncthreads();
    // scatter into segments (unordered within group)
    int st0 = 0, cn0 = 0, st1 = 0, cn1 = 0;
    if (a0) { st0 = seg[s0]; cn0 = cnt[s0]; sq[st0 + atomicAdd(&htab[s0], 1)] = e0; }
    if (a1) { st1 = seg[s1]; cn1 = cnt[s1]; sq[st1 + atomicAdd(&htab[s1], 1)] = e1; }
    __syncthreads();
    // exact rank within segment by idx (low 32 bits); idx unique -> strict <
    unsigned char* flags = (unsigned char*)flags8;
    if (a0) {
        uint32_t my = (uint32_t)e0;
        int r = 0;
        for (int q = st0; q < st0 + cn0; q++) r += ((uint32_t)sq[q] < my);
        pairA[start + st0 + r] = e0;
        if (r == 0) flags[my] = 1;
    }
    if (a1) {
        uint32_t my = (uint32_t)e1;
        int r = 0;
        for (int q = st1; q < st1 + cn1; q++) r += ((uint32_t)sq[q] < my);
        pairA[start + st1 + r] = e1;
        if (r == 0) flags[my] = 1;
    }
}

// K5: per-block bytesum of flag words (publishes partials for wp2's walk).
__global__ void vx_wpA(const u64* __restrict__ flags8, int* __restrict__ wsum, int NP8) {
    __shared__ int s[BLK];
    int t = threadIdx.x, i = blockIdx.x * BLK + t;
    u64 wv = (i < NP8) ? flags8[i] : 0ull;
    s[t] = (int)((wv * BYTEMUL) >> 56);
    __syncthreads();
    for (int o = BLK / 2; o > 0; o >>= 1) { if (t < o) s[t] += s[t + o]; __syncthreads(); }
    if (t == 0) wsum[blockIdx.x] = s[0];
}

// K6: no-spin walk over wsum + in-block scan -> wpfx; last block writes voxel_num
// (G = total head count = total flag bytes).
__global__ void vx_wp2(const u64* __restrict__ flags8, const int* __restrict__ wsum,
                       int* __restrict__ wpfx, float* __restrict__ out_vnum, int NP8) {
    __shared__ int s[BLK];
    __shared__ int eS;
    int t = threadIdx.x, b = blockIdx.x;
    if (t < 64) {
        int acc = 0;
        for (int base = 0; base < b; base += 64) {
            int idx = base + t;
            int v = (idx < b) ? wsum[idx] : 0;
            #pragma unroll
            for (int o = 32; o > 0; o >>= 1) v += __shfl_down(v, o, 64);
            acc += v;
        }
        if (t == 0) eS = acc;
    }
    int i = b * BLK + t;
    u64 wv = (i < NP8) ? flags8[i] : 0ull;
    int v = (int)((wv * BYTEMUL) >> 56);
    s[t] = v;
    __syncthreads();                        // also publishes eS
    for (int o = 1; o < BLK; o <<= 1) {
        int x = (t >= o) ? s[t - o] : 0; __syncthreads();
        s[t] += x; __syncthreads();
    }
    if (i < NP8) wpfx[i] = eS + s[t] - v;
    if (b == gridDim.x - 1 && t == BLK - 1) {
        int G = eS + s[t];
        out_vnum[0] = (float)(G < MAXV ? G : MAXV);
    }
}

__device__ __forceinline__ int vox_rank(const u64* flags8, const int* wpfx, int io) {
    int w = io >> 3, b8 = io & 7;
    u64 below = flags8[w] & ((1ull << (8 * b8)) - 1ull);
    return wpfx[w] + (int)((below * BYTEMUL) >> 56);
}

// K7: bucket-geometry emit. Group start/end are bucket-local (gpos), vid via
// flags-rank of the head's original index.
__global__ void vx_emit(const u64* __restrict__ pairA, const int* __restrict__ dtot,
                        const u64* __restrict__ flags8, const int* __restrict__ wpfx,
                        const float* __restrict__ pts, const float* __restrict__ vsz,
                        const float* __restrict__ crg, float* __restrict__ out) {
    __shared__ u64 sp[BCAP];
    __shared__ int gpos[BCAP + 1];
    __shared__ int s[BLK];
    __shared__ int sb[2];
    int t = threadIdx.x, d = blockIdx.x;
    if (t < 64) {
        int acc = 0;
        for (int j = t; j < d; j += 64) acc += dtot[j];
        #pragma unroll
        for (int o = 32; o > 0; o >>= 1) acc += __shfl_down(acc, o, 64);
        if (t == 0) { sb[0] = acc; sb[1] = dtot[d]; }
    }
    __syncthreads();
    int start = sb[0], size = sb[1];
    if (size <= 0) return;
    if (size > BCAP) size = BCAP;
    for (int i = t; i < size; i += BLK) sp[i] = pairA[start + i];
    __syncthreads();
    const int EL = BCAP / BLK;              // 4 local elements per thread
    int i0 = t * EL;
    unsigned hbits = 0; int hcnt = 0;
    #pragma unroll
    for (int r = 0; r < EL; r++) {
        int i = i0 + r;
        if (i < size) {
            int k = (int)(sp[i] >> 32);
            int h = (i == 0) || (k != (int)(sp[i - 1] >> 32));
            hbits |= (unsigned)h << r;
            hcnt += h;
        }
    }
    s[t] = hcnt;
    __syncthreads();
    for (int o = 1; o < BLK; o <<= 1) {
        int x = (t >= o) ? s[t - o] : 0; __syncthreads();
        s[t] += x; __syncthreads();
    }
    int gbase = s[t] - hcnt;                // heads before this thread's chunk
    {
        int g = gbase;
        #pragma unroll
        for (int r = 0; r < EL; r++)
            if ((hbits >> r) & 1) gpos[g++] = i0 + r;
    }
    int NG = s[BLK - 1];                    // total groups in bucket (>=1)
    if (t == 0) gpos[NG] = size;
    __syncthreads();
    int gyd = (int)rintf((crg[4] - crg[1]) / vsz[1]);
    int gzd = (int)rintf((crg[5] - crg[2]) / vsz[2]);
    int gg = gbase - 1;                     // group of element before chunk
    int cgg = -2, cvid = 0, cp0 = 0, cp1 = 0;
    #pragma unroll
    for (int r = 0; r < EL; r++) {
        int i = i0 + r;
        if (i >= size) break;
        int h = (hbits >> r) & 1;
        gg += h;
        u64 p = sp[i];
        int k = (int)(p >> 32);
        if (gg != cgg) {
            cgg = gg;
            cp0 = gpos[gg];
            cp1 = gpos[gg + 1];
            cvid = vox_rank(flags8, wpfx, (int)(sp[cp0] & 0xFFFFFFFFull));
        }
        if (cvid >= MAXV) continue;
        if (h) {                            // per-voxel work (once per group)
            int cz = k % gzd; int rr = k / gzd; int cy = rr % gyd; int cx = rr / gyd;
            out[CO_OFF + cvid * 3 + 0] = (float)cz;
            out[CO_OFF + cvid * 3 + 1] = (float)cy;
            out[CO_OFF + cvid * 3 + 2] = (float)cx;
            int gsz = cp1 - cp0;
            out[NPV_OFF + cvid] = (float)(gsz < MAXP ? gsz : MAXP);
        }
        int slot = i - cp0;
        if (slot >= MAXP) continue;
        int io = (int)(p & 0xFFFFFFFFull);
        const float* src = pts + io * C;
        float* dst = out + (cvid * MAXP + slot) * C;
        dst[0] = src[0]; dst[1] = src[1]; dst[2] = src[2]; dst[3] = src[3]; dst[4] = src[4];
    }
}

extern "C" void kernel_launch(void* const* d_in, const int* in_sizes, int n_in,
                              void* d_out, int out_size, void* d_ws, size_t ws_size,
                              hipStream_t stream) {
    if (!d_out || !d_ws || n_in < 3) return;
    const float* pts = (const float*)d_in[0];
    const float* vsz = (const float*)d_in[1];
    const float* crg = (const float*)d_in[2];
    if (!pts || !vsz || !crg) return;
    const int NP  = in_sizes[0] / C;
    if (NP <= 0) return;
    const int NB  = (NP + ELEMS - 1) / ELEMS;     // 2048-elem blocks (586)
    const int NP8 = (NP + 7) / 8;                 // byte-flag u64 words (150000)
    const int NWB = (NP8 + BLK - 1) / BLK;        // wp blocks (586)

    size_t need = (size_t)NP * 8ull                         // pairA
                + (size_t)NP * 4ull                         // key0
                + (size_t)RB * NB * 4ull                    // hist
                + (size_t)RB * 4ull                         // dtot
                + (size_t)NP8 * 8ull                        // flags8
                + (size_t)NP8 * 4ull                        // wpfx
                + (size_t)NWB * 4ull + 64ull;               // wsum + pad
    if (ws_size < need) return;
    if ((size_t)out_size < (size_t)VN_OFF + 1) return;

    u64* pairA  = (u64*)d_ws;
    int* key0   = (int*)(pairA + NP);
    int* hist   = key0 + NP;
    int* dtot   = hist + (size_t)RB * NB;
    u64* flags8 = (u64*)(dtot + RB);              // 8B-aligned (offset even #ints)
    int* wpfx   = (int*)(flags8 + NP8);
    int* wsum   = wpfx + NP8;
    float* out  = (float*)d_out;

    vx_prep<<<NB, BLK, 0, stream>>>(pts, vsz, crg, key0, hist, flags8, out, NP, NP8);
    vx_scanw<<<RB / 4, BLK, 0, stream>>>(hist, dtot, NB);
    vx_scat<<<NB, BLK, 0, stream>>>(key0, hist, dtot, pairA, NP);
    vx_group<<<RB, 512, 0, stream>>>(pairA, dtot, flags8);
    vx_wpA<<<NWB, BLK, 0, stream>>>(flags8, wsum, NP8);
    vx_wp2<<<NWB, BLK, 0, stream>>>(flags8, wsum, wpfx, out + VN_OFF, NP8);
    vx_emit<<<RB, BLK, 0, stream>>>(pairA, dtot, flags8, wpfx, pts, vsz, crg, out);
}